// Round 9
// baseline (135.221 us; speedup 1.0000x reference)
//
#include <hip/hip_runtime.h>
#include <hip/hip_bf16.h>

typedef __attribute__((ext_vector_type(8))) short short8;
typedef __attribute__((ext_vector_type(4))) short short4_t;
typedef __attribute__((ext_vector_type(8))) float f32x8;
typedef __attribute__((ext_vector_type(4))) float f32x4;

#define MFMA16(a, b, c) __builtin_amdgcn_mfma_f32_16x16x32_bf16((a), (b), (c), 0, 0, 0)

// Problem: B=2, S=2048, D=1024, H=16, Dh=64. M = B*S = 4096. Device I/O f32.
// ws layout (bf16 elem offsets):
//   Q    @ 0         [32 bh][2048 s][64 d]   (Q pre-scaled by 0.125*log2e)
//   K    @ 4194304
//   V^T  @ 8388608   [32 bh][64 d][2048 s]
//   ctx  @ 12582912  [4096][1024]
//   xbf  @ 16777216  [4096][1024]
//   wqkv @ 20971520  [3072][1024]
//   wobf @ 24117248  [1024][1024]

static __device__ __forceinline__ short f2bf(float f) {
    __hip_bfloat16 h = __float2bfloat16(f);
    return *reinterpret_cast<short*>(&h);
}

static __device__ __forceinline__ unsigned pack2bf(float lo, float hi) {
    return ((unsigned)f2bf(lo) & 0xffffu) | ((unsigned)f2bf(hi) << 16);
}

static __device__ __forceinline__ void g2l16(const void* g, void* l) {
    __builtin_amdgcn_global_load_lds(
        (const __attribute__((address_space(1))) void*)g,
        (__attribute__((address_space(3))) void*)l,
        16, 0, 0);
}

// ---------------- f32 -> bf16 convert pre-pass ----------------
__global__ __launch_bounds__(256) void cvt_kernel(
    const float* __restrict__ x,  const float* __restrict__ wq,
    const float* __restrict__ wk, const float* __restrict__ wv,
    const float* __restrict__ wo, __hip_bfloat16* __restrict__ ws)
{
    const size_t e = ((size_t)blockIdx.x * 256 + threadIdx.x) * 8;
    const float* src;
    __hip_bfloat16* dst;
    size_t off;
    if (e < 4194304)      { src = x;  dst = ws + 16777216; off = e; }
    else if (e < 5242880) { src = wq; dst = ws + 20971520; off = e - 4194304; }
    else if (e < 6291456) { src = wk; dst = ws + 20971520 + 1048576; off = e - 5242880; }
    else if (e < 7340032) { src = wv; dst = ws + 20971520 + 2097152; off = e - 6291456; }
    else                  { src = wo; dst = ws + 24117248; off = e - 7340032; }

    f32x8 v = *reinterpret_cast<const f32x8*>(src + off);
    short8 o;
#pragma unroll
    for (int j = 0; j < 8; ++j) o[j] = f2bf(v[j]);
    *reinterpret_cast<short8*>(reinterpret_cast<short*>(dst) + off) = o;
}

// ---------------- QKV projection GEMM (bf16, BK=32 double-buffered) ----------------
// 768 blocks x 256 threads. XCD-chunked. 2-phase pipeline: stage(next) issued
// before compute(cur); one vmcnt(0)+barrier per step. Q/K blocks use swapped
// MFMA operands (row=n, col=m) so each lane holds 4 consecutive d -> short4 store.
__global__ __launch_bounds__(256) void qkv_gemm_kernel(
    const __hip_bfloat16* __restrict__ xbf_,
    const __hip_bfloat16* __restrict__ wqkv_,
    __hip_bfloat16* __restrict__ qkv_out)
{
    const int bid = blockIdx.x;
    const int xcd = bid & 7, kb = bid >> 3;
    const int mBlk = xcd * 4 + (kb / 24);
    const int nBlk = kb % 24;

    const int tid  = threadIdx.x;
    const int lane = tid & 63;
    const int wid  = tid >> 6;
    const int l16  = lane & 15;
    const int lhi  = lane >> 4;
    const int wr = wid >> 1, wc = wid & 1;

    const short* A = reinterpret_cast<const short*>(xbf_);
    const short* Bm = reinterpret_cast<const short*>(wqkv_);
    const int r0A = mBlk * 128, r0B = nBlk * 128;

    const int nTileBase = nBlk * 128 + wc * 64;
    const int mat = (nTileBase >> 10);            // block-uniform: 0=q 1=k 2=v
    const bool swp = (mat < 2);

    // double-buffered 128x32 tiles (8KB each)
    __shared__ __align__(16) short sA[2][128 * 32];
    __shared__ __align__(16) short sB[2][128 * 32];

    f32x4 acc[4][4] = {};

    // stage: per matrix 512 granules of 16B; thread t covers G = t and t+256.
    auto stage = [&](int buf, int kk) {
#pragma unroll
        for (int it = 0; it < 2; ++it) {
            const int G = it * 256 + tid;
            const int row = G >> 2, gs = G & 3;
            const int gl = gs ^ (row & 3);
            g2l16(A + (size_t)(r0A + row) * 1024 + kk + gl * 8,
                  &sA[buf][(size_t)G * 8]);
            g2l16(Bm + (size_t)(r0B + row) * 1024 + kk + gl * 8,
                  &sB[buf][(size_t)G * 8]);
        }
    };

    stage(0, 0);
    asm volatile("s_waitcnt vmcnt(0)" ::: "memory");
    __syncthreads();

    int cur = 0;
#pragma unroll 1
    for (int kk = 0; kk < 1024; kk += 32) {
        if (kk + 32 < 1024) stage(cur ^ 1, kk + 32);

        short8 a[4], b[4];
#pragma unroll
        for (int i = 0; i < 4; ++i) {
            const int row = wr * 64 + i * 16 + l16;
            const int sg = lhi ^ (row & 3);
            a[i] = *reinterpret_cast<const short8*>(&sA[cur][row * 32 + sg * 8]);
        }
#pragma unroll
        for (int j = 0; j < 4; ++j) {
            const int row = wc * 64 + j * 16 + l16;
            const int sg = lhi ^ (row & 3);
            b[j] = *reinterpret_cast<const short8*>(&sB[cur][row * 32 + sg * 8]);
        }
        if (swp) {
#pragma unroll
            for (int i = 0; i < 4; ++i)
#pragma unroll
                for (int j = 0; j < 4; ++j)
                    acc[i][j] = MFMA16(b[j], a[i], acc[i][j]);
        } else {
#pragma unroll
            for (int i = 0; i < 4; ++i)
#pragma unroll
                for (int j = 0; j < 4; ++j)
                    acc[i][j] = MFMA16(a[i], b[j], acc[i][j]);
        }

        asm volatile("s_waitcnt vmcnt(0)" ::: "memory");
        __syncthreads();
        cur ^= 1;
    }

    __hip_bfloat16* dst = qkv_out + (size_t)mat * 4194304;
    const int mBase = r0A + wr * 64;

    if (swp) {
        // swapped D: row = n (lhi*4+r), col = m (l16) -> 4 consecutive d per lane
        const float qscl = (mat == 0) ? 0.18033688f : 1.0f;  // 0.125*log2e for Q
#pragma unroll
        for (int i = 0; i < 4; ++i) {
            const int mRow = mBase + i * 16 + l16;
            const int bb = mRow >> 11, s = mRow & 2047;
#pragma unroll
            for (int j = 0; j < 4; ++j) {
                const int nCol0 = (nTileBase + j * 16 + lhi * 4) & 1023;
                const int h = nCol0 >> 6, d0 = nCol0 & 63;
                short4_t v4;
#pragma unroll
                for (int r = 0; r < 4; ++r) v4[r] = f2bf(acc[i][j][r] * qscl);
                *reinterpret_cast<short4_t*>(
                    reinterpret_cast<short*>(dst) +
                    (((size_t)(bb * 16 + h) * 2048 + s) << 6) + d0) = v4;
            }
        }
    } else {
        // V transposed per head: [bh][d][s]; lane's 4 r-values = 4 consecutive s
#pragma unroll
        for (int i = 0; i < 4; ++i) {
            const int mRow0 = mBase + i * 16 + lhi * 4;
            const int bb = mRow0 >> 11, s0 = mRow0 & 2047;
#pragma unroll
            for (int j = 0; j < 4; ++j) {
                const int nCol = (nTileBase + j * 16 + l16) & 1023;
                const int h = nCol >> 6, d = nCol & 63;
                short4_t v4;
#pragma unroll
                for (int r = 0; r < 4; ++r) v4[r] = f2bf(acc[i][j][r]);
                *reinterpret_cast<short4_t*>(
                    reinterpret_cast<short*>(dst) +
                    (((size_t)(bb * 16 + h) * 64 + d) << 11) + s0) = v4;
            }
        }
    }
}

// ---------------- Flash attention — UNCHANGED from R8 ----------------
__global__ __launch_bounds__(512, 4) void attn_kernel(
    const __hip_bfloat16* __restrict__ qkv,
    __hip_bfloat16* __restrict__ ctx)
{
    const int tid  = threadIdx.x;
    const int lane = tid & 63;
    const int wid  = tid >> 6;
    const int l16 = lane & 15;
    const int lhi = lane >> 4;

    const int bid = blockIdx.x;
    const int xcd = bid & 7, idx = bid >> 3;
    const int h4 = idx & 3, tg = idx >> 2;
    const int bh = xcd * 4 + h4;
    const int g  = 15 - tg;
    const int qt = g * 8 + wid;
    const int q0 = qt * 16;
    const int sd = q0 >> 6;
    const int ns_blk = 2 * g + 2;

    const short* Q  = reinterpret_cast<const short*>(qkv) + (size_t)bh * 131072;
    const short* K  = Q + 4194304;
    const short* Vt = Q + 8388608;

    __shared__ __align__(16) short sK[2][64 * 64];
    __shared__ __align__(16) short sV[2][64 * 64];
    __shared__ __align__(16) short p_lds_all[8][16 * 72];
    short* p_lds = p_lds_all[wid];

    const int bb = bh >> 4, h = bh & 15;

    short8 qf[2];
    qf[0] = *reinterpret_cast<const short8*>(Q + (size_t)(q0 + l16) * 64 + lhi * 8);
    qf[1] = *reinterpret_cast<const short8*>(Q + (size_t)(q0 + l16) * 64 + 32 + lhi * 8);

    f32x4 oacc[4] = {};
    float lsum = 0.0f;

    const int srow = tid >> 3, sgs = tid & 7;
    const int sgl = sgs ^ (srow & 7);
    auto stage = [&](int buf, int kv0) {
        g2l16(K + (size_t)(kv0 + srow) * 64 + sgl * 8, &sK[buf][(size_t)tid * 8]);
        g2l16(Vt + (size_t)srow * 2048 + kv0 + sgl * 8, &sV[buf][(size_t)tid * 8]);
    };

    stage(0, 0);
    asm volatile("s_waitcnt vmcnt(0)" ::: "memory");
    __syncthreads();

    const int r7 = l16 & 7;
    int cur = 0;
#pragma unroll 1
    for (int st = 0; st < ns_blk; ++st) {
        const int kv0 = st * 64;
        if (st + 1 < ns_blk) stage(cur ^ 1, kv0 + 64);

        if (st <= sd) {
            f32x4 sc[4];
#pragma unroll
            for (int nt = 0; nt < 4; ++nt) {
                f32x4 s = {};
#pragma unroll
                for (int ks = 0; ks < 2; ++ks) {
                    const int sg = (ks * 4 + lhi) ^ r7;
                    short8 kb = *reinterpret_cast<const short8*>(
                        &sK[cur][(nt * 16 + l16) * 64 + sg * 8]);
                    s = MFMA16(kb, qf[ks], s);
                }
                sc[nt] = s;
            }

            if (st == sd) {
#pragma unroll
                for (int nt = 0; nt < 4; ++nt) {
                    const int kvb = kv0 + nt * 16 + lhi * 4;
                    const int qrow = q0 + l16;
#pragma unroll
                    for (int r = 0; r < 4; ++r)
                        if (kvb + r > qrow) sc[nt][r] = -1.0e38f;
                }
            }
#pragma unroll
            for (int nt = 0; nt < 4; ++nt) {
                const float p0 = exp2f(sc[nt][0]);
                const float p1 = exp2f(sc[nt][1]);
                const float p2 = exp2f(sc[nt][2]);
                const float p3 = exp2f(sc[nt][3]);
                lsum += (p0 + p1) + (p2 + p3);
                uint2 w;
                w.x = pack2bf(p0, p1);
                w.y = pack2bf(p2, p3);
                *reinterpret_cast<uint2*>(&p_lds[l16 * 72 + nt * 16 + lhi * 4]) = w;
            }
            asm volatile("s_waitcnt lgkmcnt(0)" ::: "memory");

#pragma unroll
            for (int ks = 0; ks < 2; ++ks) {
                short8 pf = *reinterpret_cast<const short8*>(
                    &p_lds[l16 * 72 + ks * 32 + lhi * 8]);
#pragma unroll
                for (int dt = 0; dt < 4; ++dt) {
                    const int sg = (ks * 4 + lhi) ^ r7;
                    short8 vb = *reinterpret_cast<const short8*>(
                        &sV[cur][(dt * 16 + l16) * 64 + sg * 8]);
                    oacc[dt] = MFMA16(pf, vb, oacc[dt]);
                }
            }
        }

        asm volatile("s_waitcnt vmcnt(0)" ::: "memory");
        __syncthreads();
        cur ^= 1;
    }

    float rs = lsum;
    rs += __shfl_xor(rs, 16);
    rs += __shfl_xor(rs, 32);
    const float rinvq = 1.0f / rs;
    float rinv[4];
#pragma unroll
    for (int r = 0; r < 4; ++r) rinv[r] = __shfl(rinvq, lhi * 4 + r);

#pragma unroll
    for (int dt = 0; dt < 4; ++dt)
#pragma unroll
        for (int r = 0; r < 4; ++r) {
            const int q = q0 + lhi * 4 + r;
            ctx[((size_t)bb * 2048 + q) * 1024 + h * 64 + dt * 16 + l16] =
                __float2bfloat16(oacc[dt][r] * rinv[r]);
        }
}

// ---------------- Output projection GEMM + bias (BK=32 double-buffered) ----------------
__global__ __launch_bounds__(256) void out_gemm_kernel(
    const __hip_bfloat16* __restrict__ ctx,
    const __hip_bfloat16* __restrict__ wobf,
    const float* __restrict__ bo,
    float* __restrict__ out)
{
    const int bid = blockIdx.x;
    const int xcd = bid & 7, kb = bid >> 3;
    const int mBlk = xcd * 4 + (kb >> 3);
    const int nBlk = kb & 7;

    const int tid  = threadIdx.x;
    const int lane = tid & 63;
    const int wid  = tid >> 6;
    const int l16  = lane & 15;
    const int lhi  = lane >> 4;
    const int wr = wid >> 1, wc = wid & 1;

    const short* A = reinterpret_cast<const short*>(ctx);
    const short* Bm = reinterpret_cast<const short*>(wobf);
    const int r0A = mBlk * 128, r0B = nBlk * 128;

    __shared__ __align__(16) short sA[2][128 * 32];
    __shared__ __align__(16) short sB[2][128 * 32];

    f32x4 acc[4][4] = {};

    auto stage = [&](int buf, int kk) {
#pragma unroll
        for (int it = 0; it < 2; ++it) {
            const int G = it * 256 + tid;
            const int row = G >> 2, gs = G & 3;
            const int gl = gs ^ (row & 3);
            g2l16(A + (size_t)(r0A + row) * 1024 + kk + gl * 8,
                  &sA[buf][(size_t)G * 8]);
            g2l16(Bm + (size_t)(r0B + row) * 1024 + kk + gl * 8,
                  &sB[buf][(size_t)G * 8]);
        }
    };

    stage(0, 0);
    asm volatile("s_waitcnt vmcnt(0)" ::: "memory");
    __syncthreads();

    int cur = 0;
#pragma unroll 1
    for (int kk = 0; kk < 1024; kk += 32) {
        if (kk + 32 < 1024) stage(cur ^ 1, kk + 32);

        short8 a[4], b[4];
#pragma unroll
        for (int i = 0; i < 4; ++i) {
            const int row = wr * 64 + i * 16 + l16;
            const int sg = lhi ^ (row & 3);
            a[i] = *reinterpret_cast<const short8*>(&sA[cur][row * 32 + sg * 8]);
        }
#pragma unroll
        for (int j = 0; j < 4; ++j) {
            const int row = wc * 64 + j * 16 + l16;
            const int sg = lhi ^ (row & 3);
            b[j] = *reinterpret_cast<const short8*>(&sB[cur][row * 32 + sg * 8]);
        }
#pragma unroll
        for (int i = 0; i < 4; ++i)
#pragma unroll
            for (int j = 0; j < 4; ++j)
                acc[i][j] = MFMA16(a[i], b[j], acc[i][j]);

        asm volatile("s_waitcnt vmcnt(0)" ::: "memory");
        __syncthreads();
        cur ^= 1;
    }

    const int mBase = r0A + wr * 64;
    const int nBase = r0B + wc * 64;
#pragma unroll
    for (int i = 0; i < 4; ++i)
#pragma unroll
        for (int j = 0; j < 4; ++j)
#pragma unroll
            for (int r = 0; r < 4; ++r) {
                const int mRow = mBase + i * 16 + lhi * 4 + r;
                const int nCol = nBase + j * 16 + l16;
                out[(size_t)mRow * 1024 + nCol] = acc[i][j][r] + bo[nCol];
            }
}

extern "C" void kernel_launch(void* const* d_in, const int* in_sizes, int n_in,
                              void* d_out, int out_size, void* d_ws, size_t ws_size,
                              hipStream_t stream) {
    const float* x  = (const float*)d_in[0];
    const float* wq = (const float*)d_in[1];
    const float* wk = (const float*)d_in[2];
    const float* wv = (const float*)d_in[3];
    const float* wo = (const float*)d_in[4];
    const float* bo = (const float*)d_in[5];

    __hip_bfloat16* ws = (__hip_bfloat16*)d_ws;
    __hip_bfloat16* ctx  = ws + 12582912;
    __hip_bfloat16* xbf  = ws + 16777216;
    __hip_bfloat16* wqkv = ws + 20971520;
    __hip_bfloat16* wobf = ws + 24117248;
    float* out = (float*)d_out;

    cvt_kernel<<<4096, 256, 0, stream>>>(x, wq, wk, wv, wo, ws);
    qkv_gemm_kernel<<<768, 256, 0, stream>>>(xbf, wqkv, ws);
    attn_kernel<<<512, 512, 0, stream>>>(ws, ctx);
    out_gemm_kernel<<<256, 256, 0, stream>>>(ctx, wobf, bo, out);
}

// Round 10
// 132.103 us; speedup vs baseline: 1.0236x; 1.0236x over previous
//
#include <hip/hip_runtime.h>
#include <hip/hip_bf16.h>

typedef __attribute__((ext_vector_type(8))) short short8;
typedef __attribute__((ext_vector_type(4))) short short4_t;
typedef __attribute__((ext_vector_type(8))) float f32x8;
typedef __attribute__((ext_vector_type(4))) float f32x4;

#define MFMA16(a, b, c) __builtin_amdgcn_mfma_f32_16x16x32_bf16((a), (b), (c), 0, 0, 0)

// Problem: B=2, S=2048, D=1024, H=16, Dh=64. M = B*S = 4096. Device I/O f32.
// ws layout (bf16 elem offsets):
//   Q    @ 0         [32 bh][2048 s][64 d]   (Q pre-scaled by 0.125*log2e)
//   K    @ 4194304
//   V^T  @ 8388608   [32 bh][64 d][2048 s]
//   ctx  @ 12582912  [4096][1024]
//   xbf  @ 16777216  [4096][1024]
//   wqkv @ 20971520  [3072][1024]
//   wobf @ 24117248  [1024][1024]

static __device__ __forceinline__ short f2bf(float f) {
    __hip_bfloat16 h = __float2bfloat16(f);
    return *reinterpret_cast<short*>(&h);
}

static __device__ __forceinline__ unsigned pack2bf(float lo, float hi) {
    return ((unsigned)f2bf(lo) & 0xffffu) | ((unsigned)f2bf(hi) << 16);
}

static __device__ __forceinline__ void g2l16(const void* g, void* l) {
    __builtin_amdgcn_global_load_lds(
        (const __attribute__((address_space(1))) void*)g,
        (__attribute__((address_space(3))) void*)l,
        16, 0, 0);
}

// ---------------- f32 -> bf16 convert pre-pass ----------------
__global__ __launch_bounds__(256) void cvt_kernel(
    const float* __restrict__ x,  const float* __restrict__ wq,
    const float* __restrict__ wk, const float* __restrict__ wv,
    const float* __restrict__ wo, __hip_bfloat16* __restrict__ ws)
{
    const size_t e = ((size_t)blockIdx.x * 256 + threadIdx.x) * 8;
    const float* src;
    __hip_bfloat16* dst;
    size_t off;
    if (e < 4194304)      { src = x;  dst = ws + 16777216; off = e; }
    else if (e < 5242880) { src = wq; dst = ws + 20971520; off = e - 4194304; }
    else if (e < 6291456) { src = wk; dst = ws + 20971520 + 1048576; off = e - 5242880; }
    else if (e < 7340032) { src = wv; dst = ws + 20971520 + 2097152; off = e - 6291456; }
    else                  { src = wo; dst = ws + 24117248; off = e - 7340032; }

    f32x8 v = *reinterpret_cast<const f32x8*>(src + off);
    short8 o;
#pragma unroll
    for (int j = 0; j < 8; ++j) o[j] = f2bf(v[j]);
    *reinterpret_cast<short8*>(reinterpret_cast<short*>(dst) + off) = o;
}

// ---------------- QKV projection GEMM (bf16, LDS-staged) — R8 proven version ----------------
// Q is pre-scaled by 0.125*log2(e) so attention needs no per-score multiply.
__global__ __launch_bounds__(256) void qkv_gemm_kernel(
    const __hip_bfloat16* __restrict__ xbf_,
    const __hip_bfloat16* __restrict__ wqkv_,
    __hip_bfloat16* __restrict__ qkv_out)
{
    const int bid = blockIdx.x;
    const int xcd = bid & 7, kb = bid >> 3;
    const int mBlk = xcd * 4 + (kb / 24);
    const int nBlk = kb % 24;

    const int tid  = threadIdx.x;
    const int lane = tid & 63;
    const int wid  = tid >> 6;
    const int l16  = lane & 15;
    const int lhi  = lane >> 4;
    const int wr = wid >> 1, wc = wid & 1;

    const short* A = reinterpret_cast<const short*>(xbf_);
    const short* Bm = reinterpret_cast<const short*>(wqkv_);
    const int r0A = mBlk * 128, r0B = nBlk * 128;

    __shared__ __align__(16) short sA[128 * 64];
    __shared__ __align__(16) short sB[128 * 64];

    f32x4 acc[4][4] = {};

    for (int kk = 0; kk < 1024; kk += 64) {
#pragma unroll
        for (int it = 0; it < 4; ++it) {
            const int G = it * 256 + tid;
            const int row = G >> 3, gs = G & 7;
            const int gl = gs ^ (row & 7);
            short* lp = sA + (size_t)(it * 256 + wid * 64) * 8;
            g2l16(A + (size_t)(r0A + row) * 1024 + kk + gl * 8, lp);
        }
#pragma unroll
        for (int it = 0; it < 4; ++it) {
            const int G = it * 256 + tid;
            const int row = G >> 3, gs = G & 7;
            const int gl = gs ^ (row & 7);
            short* lp = sB + (size_t)(it * 256 + wid * 64) * 8;
            g2l16(Bm + (size_t)(r0B + row) * 1024 + kk + gl * 8, lp);
        }
        __syncthreads();

#pragma unroll
        for (int ks = 0; ks < 2; ++ks) {
            short8 a[4], b[4];
#pragma unroll
            for (int i = 0; i < 4; ++i) {
                const int row = wr * 64 + i * 16 + l16;
                const int sg = (ks * 4 + lhi) ^ (row & 7);
                a[i] = *reinterpret_cast<const short8*>(&sA[row * 64 + sg * 8]);
            }
#pragma unroll
            for (int j = 0; j < 4; ++j) {
                const int row = wc * 64 + j * 16 + l16;
                const int sg = (ks * 4 + lhi) ^ (row & 7);
                b[j] = *reinterpret_cast<const short8*>(&sB[row * 64 + sg * 8]);
            }
#pragma unroll
            for (int i = 0; i < 4; ++i)
#pragma unroll
                for (int j = 0; j < 4; ++j)
                    acc[i][j] = MFMA16(a[i], b[j], acc[i][j]);
        }
        __syncthreads();
    }

    const int nTileBase = nBlk * 128 + wc * 64;
    const int mat = (nTileBase >> 10);
    __hip_bfloat16* dst = qkv_out + (size_t)mat * 4194304;
    const int mBase = r0A + wr * 64;

    if (mat < 2) {
        const float qscl = (mat == 0) ? 0.18033688f : 1.0f;  // 0.125*log2e for Q
#pragma unroll
        for (int i = 0; i < 4; ++i)
#pragma unroll
            for (int j = 0; j < 4; ++j)
#pragma unroll
                for (int r = 0; r < 4; ++r) {
                    const int mRow = mBase + i * 16 + lhi * 4 + r;
                    const int nCol = (nTileBase + j * 16 + l16) & 1023;
                    const int bb = mRow >> 11, s = mRow & 2047;
                    const int h = nCol >> 6, d = nCol & 63;
                    dst[(((size_t)(bb * 16 + h) * 2048 + s) << 6) + d] =
                        __float2bfloat16(acc[i][j][r] * qscl);
                }
    } else {
#pragma unroll
        for (int i = 0; i < 4; ++i) {
            const int mRow0 = mBase + i * 16 + lhi * 4;
            const int bb = mRow0 >> 11, s0 = mRow0 & 2047;
#pragma unroll
            for (int j = 0; j < 4; ++j) {
                const int nCol = (nTileBase + j * 16 + l16) & 1023;
                const int h = nCol >> 6, d = nCol & 63;
                short4_t v4;
#pragma unroll
                for (int r = 0; r < 4; ++r) v4[r] = f2bf(acc[i][j][r]);
                *reinterpret_cast<short4_t*>(
                    reinterpret_cast<short*>(dst) +
                    (((size_t)(bb * 16 + h) * 64 + d) << 11) + s0) = v4;
            }
        }
    }
}

// ---------------- Flash attention (causal), uniform complementary-segment blocks ----
// 256 blocks x 512 threads (8 waves). Block = head bh, pair index bp in [0,8):
// processes segment g=15-bp then g=bp (8 q-tiles each, wave wid -> tile g*8+wid).
// Every block runs exactly (2(15-bp)+2)+(2bp+2) = 34 KV-steps -> uniform load on
// every CU with zero scheduler assumptions. K/V double-buffered in LDS; swapped
// QK^T; fixed-shift softmax; mask only on each wave's diagonal step.
__global__ __launch_bounds__(512, 4) void attn_kernel(
    const __hip_bfloat16* __restrict__ qkv,
    __hip_bfloat16* __restrict__ ctx)
{
    const int tid  = threadIdx.x;
    const int lane = tid & 63;
    const int wid  = tid >> 6;               // 0..7
    const int l16 = lane & 15;
    const int lhi = lane >> 4;

    const int bid = blockIdx.x;              // 256 blocks
    const int xcd = bid & 7, idx = bid >> 3; // idx 0..31
    const int h4 = idx & 3, bp = idx >> 2;   // bp 0..7
    const int bh = xcd * 4 + h4;

    const short* Q  = reinterpret_cast<const short*>(qkv) + (size_t)bh * 131072;
    const short* K  = Q + 4194304;
    const short* Vt = Q + 8388608;

    __shared__ __align__(16) short sK[2][64 * 64];
    __shared__ __align__(16) short sV[2][64 * 64];
    __shared__ __align__(16) short p_lds_all[8][16 * 72];
    short* p_lds = p_lds_all[wid];

    const int bb = bh >> 4, h = bh & 15;

    const int srow = tid >> 3, sgs = tid & 7;
    const int sgl = sgs ^ (srow & 7);
    auto stage = [&](int buf, int kv0) {
        g2l16(K + (size_t)(kv0 + srow) * 64 + sgl * 8, &sK[buf][(size_t)tid * 8]);
        g2l16(Vt + (size_t)srow * 2048 + kv0 + sgl * 8, &sV[buf][(size_t)tid * 8]);
    };

    const int r7 = l16 & 7;

#pragma unroll 1
    for (int seg = 0; seg < 2; ++seg) {
        const int g  = seg ? bp : (15 - bp);
        const int qt = g * 8 + wid;
        const int q0 = qt * 16;
        const int sd = q0 >> 6;              // this wave's diagonal step
        const int ns_blk = 2 * g + 2;        // segment step count

        short8 qf[2];
        qf[0] = *reinterpret_cast<const short8*>(Q + (size_t)(q0 + l16) * 64 + lhi * 8);
        qf[1] = *reinterpret_cast<const short8*>(Q + (size_t)(q0 + l16) * 64 + 32 + lhi * 8);

        f32x4 oacc[4] = {};
        float lsum = 0.0f;

        stage(0, 0);
        asm volatile("s_waitcnt vmcnt(0)" ::: "memory");
        __syncthreads();

        int cur = 0;
#pragma unroll 1
        for (int st = 0; st < ns_blk; ++st) {
            const int kv0 = st * 64;
            if (st + 1 < ns_blk) stage(cur ^ 1, kv0 + 64);

            if (st <= sd) {
                f32x4 sc[4];
#pragma unroll
                for (int nt = 0; nt < 4; ++nt) {
                    f32x4 s = {};
#pragma unroll
                    for (int ks = 0; ks < 2; ++ks) {
                        const int sg = (ks * 4 + lhi) ^ r7;
                        short8 kb = *reinterpret_cast<const short8*>(
                            &sK[cur][(nt * 16 + l16) * 64 + sg * 8]);
                        s = MFMA16(kb, qf[ks], s);
                    }
                    sc[nt] = s;
                }

                if (st == sd) {
#pragma unroll
                    for (int nt = 0; nt < 4; ++nt) {
                        const int kvb = kv0 + nt * 16 + lhi * 4;
                        const int qrow = q0 + l16;
#pragma unroll
                        for (int r = 0; r < 4; ++r)
                            if (kvb + r > qrow) sc[nt][r] = -1.0e38f;
                    }
                }
#pragma unroll
                for (int nt = 0; nt < 4; ++nt) {
                    const float p0 = exp2f(sc[nt][0]);
                    const float p1 = exp2f(sc[nt][1]);
                    const float p2 = exp2f(sc[nt][2]);
                    const float p3 = exp2f(sc[nt][3]);
                    lsum += (p0 + p1) + (p2 + p3);
                    uint2 w;
                    w.x = pack2bf(p0, p1);
                    w.y = pack2bf(p2, p3);
                    *reinterpret_cast<uint2*>(&p_lds[l16 * 72 + nt * 16 + lhi * 4]) = w;
                }
                asm volatile("s_waitcnt lgkmcnt(0)" ::: "memory");

#pragma unroll
                for (int ks = 0; ks < 2; ++ks) {
                    short8 pf = *reinterpret_cast<const short8*>(
                        &p_lds[l16 * 72 + ks * 32 + lhi * 8]);
#pragma unroll
                    for (int dt = 0; dt < 4; ++dt) {
                        const int sg = (ks * 4 + lhi) ^ r7;
                        short8 vb = *reinterpret_cast<const short8*>(
                            &sV[cur][(dt * 16 + l16) * 64 + sg * 8]);
                        oacc[dt] = MFMA16(pf, vb, oacc[dt]);
                    }
                }
            }

            asm volatile("s_waitcnt vmcnt(0)" ::: "memory");
            __syncthreads();
            cur ^= 1;
        }

        // ---- segment epilogue: row-sum, transpose rinv, store ----
        float rs = lsum;
        rs += __shfl_xor(rs, 16);
        rs += __shfl_xor(rs, 32);
        const float rinvq = 1.0f / rs;
        float rinv[4];
#pragma unroll
        for (int r = 0; r < 4; ++r) rinv[r] = __shfl(rinvq, lhi * 4 + r);

#pragma unroll
        for (int dt = 0; dt < 4; ++dt)
#pragma unroll
            for (int r = 0; r < 4; ++r) {
                const int q = q0 + lhi * 4 + r;
                ctx[((size_t)bb * 2048 + q) * 1024 + h * 64 + dt * 16 + l16] =
                    __float2bfloat16(oacc[dt][r] * rinv[r]);
            }
    }
}

// ---------------- Output projection GEMM + bias — R8 proven version ----------------
__global__ __launch_bounds__(256) void out_gemm_kernel(
    const __hip_bfloat16* __restrict__ ctx,
    const __hip_bfloat16* __restrict__ wobf,
    const float* __restrict__ bo,
    float* __restrict__ out)
{
    const int bid = blockIdx.x;
    const int xcd = bid & 7, kb = bid >> 3;
    const int mBlk = xcd * 4 + (kb >> 3);
    const int nBlk = kb & 7;

    const int tid  = threadIdx.x;
    const int lane = tid & 63;
    const int wid  = tid >> 6;
    const int l16  = lane & 15;
    const int lhi  = lane >> 4;
    const int wr = wid >> 1, wc = wid & 1;

    const short* A = reinterpret_cast<const short*>(ctx);
    const short* Bm = reinterpret_cast<const short*>(wobf);
    const int r0A = mBlk * 128, r0B = nBlk * 128;

    __shared__ __align__(16) short sA[128 * 64];
    __shared__ __align__(16) short sB[128 * 64];

    f32x4 acc[4][4] = {};

    for (int kk = 0; kk < 1024; kk += 64) {
#pragma unroll
        for (int it = 0; it < 4; ++it) {
            const int G = it * 256 + tid;
            const int row = G >> 3, gs = G & 7;
            const int gl = gs ^ (row & 7);
            short* lp = sA + (size_t)(it * 256 + wid * 64) * 8;
            g2l16(A + (size_t)(r0A + row) * 1024 + kk + gl * 8, lp);
        }
#pragma unroll
        for (int it = 0; it < 4; ++it) {
            const int G = it * 256 + tid;
            const int row = G >> 3, gs = G & 7;
            const int gl = gs ^ (row & 7);
            short* lp = sB + (size_t)(it * 256 + wid * 64) * 8;
            g2l16(Bm + (size_t)(r0B + row) * 1024 + kk + gl * 8, lp);
        }
        __syncthreads();

#pragma unroll
        for (int ks = 0; ks < 2; ++ks) {
            short8 a[4], b[4];
#pragma unroll
            for (int i = 0; i < 4; ++i) {
                const int row = wr * 64 + i * 16 + l16;
                const int sg = (ks * 4 + lhi) ^ (row & 7);
                a[i] = *reinterpret_cast<const short8*>(&sA[row * 64 + sg * 8]);
            }
#pragma unroll
            for (int j = 0; j < 4; ++j) {
                const int row = wc * 64 + j * 16 + l16;
                const int sg = (ks * 4 + lhi) ^ (row & 7);
                b[j] = *reinterpret_cast<const short8*>(&sB[row * 64 + sg * 8]);
            }
#pragma unroll
            for (int i = 0; i < 4; ++i)
#pragma unroll
                for (int j = 0; j < 4; ++j)
                    acc[i][j] = MFMA16(a[i], b[j], acc[i][j]);
        }
        __syncthreads();
    }

    const int mBase = r0A + wr * 64;
    const int nBase = r0B + wc * 64;
#pragma unroll
    for (int i = 0; i < 4; ++i)
#pragma unroll
        for (int j = 0; j < 4; ++j)
#pragma unroll
            for (int r = 0; r < 4; ++r) {
                const int mRow = mBase + i * 16 + lhi * 4 + r;
                const int nCol = nBase + j * 16 + l16;
                out[(size_t)mRow * 1024 + nCol] = acc[i][j][r] + bo[nCol];
            }
}

extern "C" void kernel_launch(void* const* d_in, const int* in_sizes, int n_in,
                              void* d_out, int out_size, void* d_ws, size_t ws_size,
                              hipStream_t stream) {
    const float* x  = (const float*)d_in[0];
    const float* wq = (const float*)d_in[1];
    const float* wk = (const float*)d_in[2];
    const float* wv = (const float*)d_in[3];
    const float* wo = (const float*)d_in[4];
    const float* bo = (const float*)d_in[5];

    __hip_bfloat16* ws = (__hip_bfloat16*)d_ws;
    __hip_bfloat16* ctx  = ws + 12582912;
    __hip_bfloat16* xbf  = ws + 16777216;
    __hip_bfloat16* wqkv = ws + 20971520;
    __hip_bfloat16* wobf = ws + 24117248;
    float* out = (float*)d_out;

    cvt_kernel<<<4096, 256, 0, stream>>>(x, wq, wk, wv, wo, ws);
    qkv_gemm_kernel<<<768, 256, 0, stream>>>(xbf, wqkv, ws);
    attn_kernel<<<256, 512, 0, stream>>>(ws, ctx);
    out_gemm_kernel<<<256, 256, 0, stream>>>(ctx, wobf, bo, out);
}

// Round 11
// 118.223 us; speedup vs baseline: 1.1438x; 1.1174x over previous
//
#include <hip/hip_runtime.h>
#include <hip/hip_bf16.h>

typedef __attribute__((ext_vector_type(8))) short short8;
typedef __attribute__((ext_vector_type(4))) short short4_t;
typedef __attribute__((ext_vector_type(8))) float f32x8;
typedef __attribute__((ext_vector_type(4))) float f32x4;

#define MFMA16(a, b, c) __builtin_amdgcn_mfma_f32_16x16x32_bf16((a), (b), (c), 0, 0, 0)

// Problem: B=2, S=2048, D=1024, H=16, Dh=64. M = B*S = 4096. Device I/O f32.
// ws layout (bf16 elem offsets):
//   Q    @ 0         [32 bh][2048 s][64 d]   (Q pre-scaled by 0.125*log2e)
//   K    @ 4194304
//   V^T  @ 8388608   [32 bh][64 d][2048 s]
//   ctx  @ 12582912  [4096][1024]
//   xbf  @ 16777216  [4096][1024]
//   wqkv @ 20971520  [3072][1024]
//   wobf @ 24117248  [1024][1024]

static __device__ __forceinline__ short f2bf(float f) {
    __hip_bfloat16 h = __float2bfloat16(f);
    return *reinterpret_cast<short*>(&h);
}

static __device__ __forceinline__ unsigned pack2bf(float lo, float hi) {
    return ((unsigned)f2bf(lo) & 0xffffu) | ((unsigned)f2bf(hi) << 16);
}

static __device__ __forceinline__ void g2l16(const void* g, void* l) {
    __builtin_amdgcn_global_load_lds(
        (const __attribute__((address_space(1))) void*)g,
        (__attribute__((address_space(3))) void*)l,
        16, 0, 0);
}

// ---------------- f32 -> bf16 convert pre-pass ----------------
__global__ __launch_bounds__(256) void cvt_kernel(
    const float* __restrict__ x,  const float* __restrict__ wq,
    const float* __restrict__ wk, const float* __restrict__ wv,
    const float* __restrict__ wo, __hip_bfloat16* __restrict__ ws)
{
    const size_t e = ((size_t)blockIdx.x * 256 + threadIdx.x) * 8;
    const float* src;
    __hip_bfloat16* dst;
    size_t off;
    if (e < 4194304)      { src = x;  dst = ws + 16777216; off = e; }
    else if (e < 5242880) { src = wq; dst = ws + 20971520; off = e - 4194304; }
    else if (e < 6291456) { src = wk; dst = ws + 20971520 + 1048576; off = e - 5242880; }
    else if (e < 7340032) { src = wv; dst = ws + 20971520 + 2097152; off = e - 6291456; }
    else                  { src = wo; dst = ws + 24117248; off = e - 7340032; }

    f32x8 v = *reinterpret_cast<const f32x8*>(src + off);
    short8 o;
#pragma unroll
    for (int j = 0; j < 8; ++j) o[j] = f2bf(v[j]);
    *reinterpret_cast<short8*>(reinterpret_cast<short*>(dst) + off) = o;
}

// ---------------- QKV projection GEMM (bf16, LDS-staged) — R8 proven version ----------------
// Q is pre-scaled by 0.125*log2(e) so attention needs no per-score multiply.
__global__ __launch_bounds__(256) void qkv_gemm_kernel(
    const __hip_bfloat16* __restrict__ xbf_,
    const __hip_bfloat16* __restrict__ wqkv_,
    __hip_bfloat16* __restrict__ qkv_out)
{
    const int bid = blockIdx.x;
    const int xcd = bid & 7, kb = bid >> 3;
    const int mBlk = xcd * 4 + (kb / 24);
    const int nBlk = kb % 24;

    const int tid  = threadIdx.x;
    const int lane = tid & 63;
    const int wid  = tid >> 6;
    const int l16  = lane & 15;
    const int lhi  = lane >> 4;
    const int wr = wid >> 1, wc = wid & 1;

    const short* A = reinterpret_cast<const short*>(xbf_);
    const short* Bm = reinterpret_cast<const short*>(wqkv_);
    const int r0A = mBlk * 128, r0B = nBlk * 128;

    __shared__ __align__(16) short sA[128 * 64];
    __shared__ __align__(16) short sB[128 * 64];

    f32x4 acc[4][4] = {};

    for (int kk = 0; kk < 1024; kk += 64) {
#pragma unroll
        for (int it = 0; it < 4; ++it) {
            const int G = it * 256 + tid;
            const int row = G >> 3, gs = G & 7;
            const int gl = gs ^ (row & 7);
            short* lp = sA + (size_t)(it * 256 + wid * 64) * 8;
            g2l16(A + (size_t)(r0A + row) * 1024 + kk + gl * 8, lp);
        }
#pragma unroll
        for (int it = 0; it < 4; ++it) {
            const int G = it * 256 + tid;
            const int row = G >> 3, gs = G & 7;
            const int gl = gs ^ (row & 7);
            short* lp = sB + (size_t)(it * 256 + wid * 64) * 8;
            g2l16(Bm + (size_t)(r0B + row) * 1024 + kk + gl * 8, lp);
        }
        __syncthreads();

#pragma unroll
        for (int ks = 0; ks < 2; ++ks) {
            short8 a[4], b[4];
#pragma unroll
            for (int i = 0; i < 4; ++i) {
                const int row = wr * 64 + i * 16 + l16;
                const int sg = (ks * 4 + lhi) ^ (row & 7);
                a[i] = *reinterpret_cast<const short8*>(&sA[row * 64 + sg * 8]);
            }
#pragma unroll
            for (int j = 0; j < 4; ++j) {
                const int row = wc * 64 + j * 16 + l16;
                const int sg = (ks * 4 + lhi) ^ (row & 7);
                b[j] = *reinterpret_cast<const short8*>(&sB[row * 64 + sg * 8]);
            }
#pragma unroll
            for (int i = 0; i < 4; ++i)
#pragma unroll
                for (int j = 0; j < 4; ++j)
                    acc[i][j] = MFMA16(a[i], b[j], acc[i][j]);
        }
        __syncthreads();
    }

    const int nTileBase = nBlk * 128 + wc * 64;
    const int mat = (nTileBase >> 10);
    __hip_bfloat16* dst = qkv_out + (size_t)mat * 4194304;
    const int mBase = r0A + wr * 64;

    if (mat < 2) {
        const float qscl = (mat == 0) ? 0.18033688f : 1.0f;  // 0.125*log2e for Q
#pragma unroll
        for (int i = 0; i < 4; ++i)
#pragma unroll
            for (int j = 0; j < 4; ++j)
#pragma unroll
                for (int r = 0; r < 4; ++r) {
                    const int mRow = mBase + i * 16 + lhi * 4 + r;
                    const int nCol = (nTileBase + j * 16 + l16) & 1023;
                    const int bb = mRow >> 11, s = mRow & 2047;
                    const int h = nCol >> 6, d = nCol & 63;
                    dst[(((size_t)(bb * 16 + h) * 2048 + s) << 6) + d] =
                        __float2bfloat16(acc[i][j][r] * qscl);
                }
    } else {
#pragma unroll
        for (int i = 0; i < 4; ++i) {
            const int mRow0 = mBase + i * 16 + lhi * 4;
            const int bb = mRow0 >> 11, s0 = mRow0 & 2047;
#pragma unroll
            for (int j = 0; j < 4; ++j) {
                const int nCol = (nTileBase + j * 16 + l16) & 1023;
                const int h = nCol >> 6, d = nCol & 63;
                short4_t v4;
#pragma unroll
                for (int r = 0; r < 4; ++r) v4[r] = f2bf(acc[i][j][r]);
                *reinterpret_cast<short4_t*>(
                    reinterpret_cast<short*>(dst) +
                    (((size_t)(bb * 16 + h) * 64 + d) << 11) + s0) = v4;
            }
        }
    }
}

// ---------------- Flash attention (causal) — R8 structure + complementary CU pairing ----
// 512 blocks x 512 threads (8 waves). Block = 8 adjacent q-tiles of ONE head.
// tg->g remap: g = tg<8 ? 15-tg : tg-8. Under round-robin dispatch, blocks bid
// and bid+256 co-reside on one CU with complementary g and SAME head ->
// every CU does exactly (2g+2)+(2(15-g)+2) = 34 block-steps, shared K/V in L2.
// Longest blocks still dispatch first (fallback if pairing assumption fails).
__global__ __launch_bounds__(512, 4) void attn_kernel(
    const __hip_bfloat16* __restrict__ qkv,
    __hip_bfloat16* __restrict__ ctx)
{
    const int tid  = threadIdx.x;
    const int lane = tid & 63;
    const int wid  = tid >> 6;               // 0..7
    const int l16 = lane & 15;
    const int lhi = lane >> 4;

    const int bid = blockIdx.x;              // 512 blocks
    const int xcd = bid & 7, idx = bid >> 3; // idx 0..63
    const int h4 = idx & 3, tg = idx >> 2;   // tg 0..15
    const int bh = xcd * 4 + h4;
    const int g  = (tg < 8) ? (15 - tg) : (tg - 8);  // complementary pairing
    const int qt = g * 8 + wid;
    const int q0 = qt * 16;
    const int sd = q0 >> 6;                  // this wave's diagonal step
    const int ns_blk = 2 * g + 2;            // block max steps

    const short* Q  = reinterpret_cast<const short*>(qkv) + (size_t)bh * 131072;
    const short* K  = Q + 4194304;
    const short* Vt = Q + 8388608;

    __shared__ __align__(16) short sK[2][64 * 64];
    __shared__ __align__(16) short sV[2][64 * 64];
    __shared__ __align__(16) short p_lds_all[8][16 * 72];
    short* p_lds = p_lds_all[wid];

    const int bb = bh >> 4, h = bh & 15;

    short8 qf[2];
    qf[0] = *reinterpret_cast<const short8*>(Q + (size_t)(q0 + l16) * 64 + lhi * 8);
    qf[1] = *reinterpret_cast<const short8*>(Q + (size_t)(q0 + l16) * 64 + 32 + lhi * 8);

    f32x4 oacc[4] = {};
    float lsum = 0.0f;

    const int srow = tid >> 3, sgs = tid & 7;
    const int sgl = sgs ^ (srow & 7);
    auto stage = [&](int buf, int kv0) {
        g2l16(K + (size_t)(kv0 + srow) * 64 + sgl * 8, &sK[buf][(size_t)tid * 8]);
        g2l16(Vt + (size_t)srow * 2048 + kv0 + sgl * 8, &sV[buf][(size_t)tid * 8]);
    };

    stage(0, 0);
    asm volatile("s_waitcnt vmcnt(0)" ::: "memory");
    __syncthreads();

    const int r7 = l16 & 7;
    int cur = 0;
#pragma unroll 1
    for (int st = 0; st < ns_blk; ++st) {
        const int kv0 = st * 64;
        if (st + 1 < ns_blk) stage(cur ^ 1, kv0 + 64);

        if (st <= sd) {
            f32x4 sc[4];
#pragma unroll
            for (int nt = 0; nt < 4; ++nt) {
                f32x4 s = {};
#pragma unroll
                for (int ks = 0; ks < 2; ++ks) {
                    const int sg = (ks * 4 + lhi) ^ r7;
                    short8 kb = *reinterpret_cast<const short8*>(
                        &sK[cur][(nt * 16 + l16) * 64 + sg * 8]);
                    s = MFMA16(kb, qf[ks], s);
                }
                sc[nt] = s;
            }

            if (st == sd) {
#pragma unroll
                for (int nt = 0; nt < 4; ++nt) {
                    const int kvb = kv0 + nt * 16 + lhi * 4;
                    const int qrow = q0 + l16;
#pragma unroll
                    for (int r = 0; r < 4; ++r)
                        if (kvb + r > qrow) sc[nt][r] = -1.0e38f;
                }
            }
#pragma unroll
            for (int nt = 0; nt < 4; ++nt) {
                const float p0 = exp2f(sc[nt][0]);
                const float p1 = exp2f(sc[nt][1]);
                const float p2 = exp2f(sc[nt][2]);
                const float p3 = exp2f(sc[nt][3]);
                lsum += (p0 + p1) + (p2 + p3);
                uint2 w;
                w.x = pack2bf(p0, p1);
                w.y = pack2bf(p2, p3);
                *reinterpret_cast<uint2*>(&p_lds[l16 * 72 + nt * 16 + lhi * 4]) = w;
            }
            asm volatile("s_waitcnt lgkmcnt(0)" ::: "memory");

#pragma unroll
            for (int ks = 0; ks < 2; ++ks) {
                short8 pf = *reinterpret_cast<const short8*>(
                    &p_lds[l16 * 72 + ks * 32 + lhi * 8]);
#pragma unroll
                for (int dt = 0; dt < 4; ++dt) {
                    const int sg = (ks * 4 + lhi) ^ r7;
                    short8 vb = *reinterpret_cast<const short8*>(
                        &sV[cur][(dt * 16 + l16) * 64 + sg * 8]);
                    oacc[dt] = MFMA16(pf, vb, oacc[dt]);
                }
            }
        }

        asm volatile("s_waitcnt vmcnt(0)" ::: "memory");
        __syncthreads();
        cur ^= 1;
    }

    float rs = lsum;
    rs += __shfl_xor(rs, 16);
    rs += __shfl_xor(rs, 32);
    const float rinvq = 1.0f / rs;
    float rinv[4];
#pragma unroll
    for (int r = 0; r < 4; ++r) rinv[r] = __shfl(rinvq, lhi * 4 + r);

#pragma unroll
    for (int dt = 0; dt < 4; ++dt)
#pragma unroll
        for (int r = 0; r < 4; ++r) {
            const int q = q0 + lhi * 4 + r;
            ctx[((size_t)bb * 2048 + q) * 1024 + h * 64 + dt * 16 + l16] =
                __float2bfloat16(oacc[dt][r] * rinv[r]);
        }
}

// ---------------- Output projection GEMM + bias — R8 proven version ----------------
__global__ __launch_bounds__(256) void out_gemm_kernel(
    const __hip_bfloat16* __restrict__ ctx,
    const __hip_bfloat16* __restrict__ wobf,
    const float* __restrict__ bo,
    float* __restrict__ out)
{
    const int bid = blockIdx.x;
    const int xcd = bid & 7, kb = bid >> 3;
    const int mBlk = xcd * 4 + (kb >> 3);
    const int nBlk = kb & 7;

    const int tid  = threadIdx.x;
    const int lane = tid & 63;
    const int wid  = tid >> 6;
    const int l16  = lane & 15;
    const int lhi  = lane >> 4;
    const int wr = wid >> 1, wc = wid & 1;

    const short* A = reinterpret_cast<const short*>(ctx);
    const short* Bm = reinterpret_cast<const short*>(wobf);
    const int r0A = mBlk * 128, r0B = nBlk * 128;

    __shared__ __align__(16) short sA[128 * 64];
    __shared__ __align__(16) short sB[128 * 64];

    f32x4 acc[4][4] = {};

    for (int kk = 0; kk < 1024; kk += 64) {
#pragma unroll
        for (int it = 0; it < 4; ++it) {
            const int G = it * 256 + tid;
            const int row = G >> 3, gs = G & 7;
            const int gl = gs ^ (row & 7);
            short* lp = sA + (size_t)(it * 256 + wid * 64) * 8;
            g2l16(A + (size_t)(r0A + row) * 1024 + kk + gl * 8, lp);
        }
#pragma unroll
        for (int it = 0; it < 4; ++it) {
            const int G = it * 256 + tid;
            const int row = G >> 3, gs = G & 7;
            const int gl = gs ^ (row & 7);
            short* lp = sB + (size_t)(it * 256 + wid * 64) * 8;
            g2l16(Bm + (size_t)(r0B + row) * 1024 + kk + gl * 8, lp);
        }
        __syncthreads();

#pragma unroll
        for (int ks = 0; ks < 2; ++ks) {
            short8 a[4], b[4];
#pragma unroll
            for (int i = 0; i < 4; ++i) {
                const int row = wr * 64 + i * 16 + l16;
                const int sg = (ks * 4 + lhi) ^ (row & 7);
                a[i] = *reinterpret_cast<const short8*>(&sA[row * 64 + sg * 8]);
            }
#pragma unroll
            for (int j = 0; j < 4; ++j) {
                const int row = wc * 64 + j * 16 + l16;
                const int sg = (ks * 4 + lhi) ^ (row & 7);
                b[j] = *reinterpret_cast<const short8*>(&sB[row * 64 + sg * 8]);
            }
#pragma unroll
            for (int i = 0; i < 4; ++i)
#pragma unroll
                for (int j = 0; j < 4; ++j)
                    acc[i][j] = MFMA16(a[i], b[j], acc[i][j]);
        }
        __syncthreads();
    }

    const int mBase = r0A + wr * 64;
    const int nBase = r0B + wc * 64;
#pragma unroll
    for (int i = 0; i < 4; ++i)
#pragma unroll
        for (int j = 0; j < 4; ++j)
#pragma unroll
            for (int r = 0; r < 4; ++r) {
                const int mRow = mBase + i * 16 + lhi * 4 + r;
                const int nCol = nBase + j * 16 + l16;
                out[(size_t)mRow * 1024 + nCol] = acc[i][j][r] + bo[nCol];
            }
}

extern "C" void kernel_launch(void* const* d_in, const int* in_sizes, int n_in,
                              void* d_out, int out_size, void* d_ws, size_t ws_size,
                              hipStream_t stream) {
    const float* x  = (const float*)d_in[0];
    const float* wq = (const float*)d_in[1];
    const float* wk = (const float*)d_in[2];
    const float* wv = (const float*)d_in[3];
    const float* wo = (const float*)d_in[4];
    const float* bo = (const float*)d_in[5];

    __hip_bfloat16* ws = (__hip_bfloat16*)d_ws;
    __hip_bfloat16* ctx  = ws + 12582912;
    __hip_bfloat16* xbf  = ws + 16777216;
    __hip_bfloat16* wqkv = ws + 20971520;
    __hip_bfloat16* wobf = ws + 24117248;
    float* out = (float*)d_out;

    cvt_kernel<<<4096, 256, 0, stream>>>(x, wq, wk, wv, wo, ws);
    qkv_gemm_kernel<<<768, 256, 0, stream>>>(xbf, wqkv, ws);
    attn_kernel<<<512, 512, 0, stream>>>(ws, ctx);
    out_gemm_kernel<<<256, 256, 0, stream>>>(ctx, wobf, bo, out);
}